// Round 2
// baseline (16581.410 us; speedup 1.0000x reference)
//
#include <hip/hip_runtime.h>
#include <cstdint>
#include <cstddef>

#define L 512
#define TSTEPS 8192
#define CHUNK 128
#define NCHUNK 64   // 8192 / 128

typedef float f4 __attribute__((ext_vector_type(4)));
typedef unsigned int u32;

// ---- workspace layout (bytes) ----
static constexpr size_t OFF_SCORES = 0;                                             // [TSTEPS][L] f32 = 16 MiB
static constexpr size_t OFF_BP     = (size_t)TSTEPS * L * sizeof(float);            // [TSTEPS][L] u16 = 8 MiB
static constexpr size_t OFF_EXIT   = OFF_BP + (size_t)TSTEPS * L * sizeof(uint16_t);// [NCHUNK][L] u16
static constexpr size_t OFF_ENTRY  = OFF_EXIT + (size_t)NCHUNK * L * sizeof(uint16_t); // [NCHUNK] i32

__device__ __forceinline__ void st_coh(float* p, float v) {
  __hip_atomic_store((uint32_t*)p, __float_as_uint(v), __ATOMIC_RELAXED, __HIP_MEMORY_SCOPE_AGENT);
}
__device__ __forceinline__ u32 myumax(u32 a, u32 b) { return a > b ? a : b; }

// ---------------- forward: barrier-free max-plus scan ----------------
// 64 blocks x 1 wave. Block b owns cols [b*8, b*8+8). Lane (c=lane>>3, g=lane&7)
// holds T[g*64 .. g*64+64)[col] in 64 VGPRs. Poll = 16x dwordx4 sc0 sc1 loads of
// scores[t-1][g*64..g*64+64) with waitcnt inside the asm; sentinel = 0xFFFFFFFF
// (unreachable by arithmetic on finite inputs; memset'd each launch).
#define POLL16(P)                                                        \
  asm volatile(                                                          \
      "global_load_dwordx4 %0, %16, off offset:0 sc0 sc1\n\t"            \
      "global_load_dwordx4 %1, %16, off offset:16 sc0 sc1\n\t"           \
      "global_load_dwordx4 %2, %16, off offset:32 sc0 sc1\n\t"           \
      "global_load_dwordx4 %3, %16, off offset:48 sc0 sc1\n\t"           \
      "global_load_dwordx4 %4, %16, off offset:64 sc0 sc1\n\t"           \
      "global_load_dwordx4 %5, %16, off offset:80 sc0 sc1\n\t"           \
      "global_load_dwordx4 %6, %16, off offset:96 sc0 sc1\n\t"           \
      "global_load_dwordx4 %7, %16, off offset:112 sc0 sc1\n\t"          \
      "global_load_dwordx4 %8, %16, off offset:128 sc0 sc1\n\t"          \
      "global_load_dwordx4 %9, %16, off offset:144 sc0 sc1\n\t"          \
      "global_load_dwordx4 %10, %16, off offset:160 sc0 sc1\n\t"         \
      "global_load_dwordx4 %11, %16, off offset:176 sc0 sc1\n\t"         \
      "global_load_dwordx4 %12, %16, off offset:192 sc0 sc1\n\t"         \
      "global_load_dwordx4 %13, %16, off offset:208 sc0 sc1\n\t"         \
      "global_load_dwordx4 %14, %16, off offset:224 sc0 sc1\n\t"         \
      "global_load_dwordx4 %15, %16, off offset:240 sc0 sc1\n\t"         \
      "s_waitcnt vmcnt(0)"                                               \
      : "=&v"(A0), "=&v"(A1), "=&v"(A2), "=&v"(A3),                      \
        "=&v"(A4), "=&v"(A5), "=&v"(A6), "=&v"(A7),                      \
        "=&v"(A8), "=&v"(A9), "=&v"(A10), "=&v"(A11),                    \
        "=&v"(A12), "=&v"(A13), "=&v"(A14), "=&v"(A15)                   \
      : "v"(P)                                                           \
      : "memory")

#define UMX(V) myumax(myumax(__float_as_uint(V.x), __float_as_uint(V.y)), \
                      myumax(__float_as_uint(V.z), __float_as_uint(V.w)))

#define ACCK(Ak, k)                                                      \
  { f4 s = Ak + Tr[k];                                                   \
    ax = fmaxf(ax, s.x); ay = fmaxf(ay, s.y);                            \
    az = fmaxf(az, s.z); aw = fmaxf(aw, s.w); }

__global__ __launch_bounds__(64) void fwd_kernel(const float* __restrict__ feats,
                                                 const float* __restrict__ trans,
                                                 float* __restrict__ scores) {
  const int lane = threadIdx.x;
  const int c    = lane >> 3;          // col within block's 8
  const int g    = lane & 7;           // row group: rows g*64 .. g*64+64
  const int col  = blockIdx.x * 8 + c;

  // stage this lane's T column-slice into registers (one-time, uncoalesced ok)
  f4 Tr[16];
  #pragma unroll
  for (int k = 0; k < 16; ++k) {
    int r = g * 64 + k * 4;
    Tr[k].x = trans[(size_t)(r + 0) * L + col];
    Tr[k].y = trans[(size_t)(r + 1) * L + col];
    Tr[k].z = trans[(size_t)(r + 2) * L + col];
    Tr[k].w = trans[(size_t)(r + 3) * L + col];
  }

  // publish t=0: scores[0] = feats[0]
  if (g == 0) st_coh(scores + col, feats[col]);

  f4 A0, A1, A2, A3, A4, A5, A6, A7, A8, A9, A10, A11, A12, A13, A14, A15;

  for (int t = 1; t < TSTEPS; ++t) {
    float e = feats[(size_t)t * L + col];  // prefetch; completes under the poll
    const float* p = scores + (size_t)(t - 1) * L + g * 64;
    for (;;) {
      POLL16(p);
      u32 mx = myumax(
          myumax(myumax(myumax(UMX(A0), UMX(A1)), myumax(UMX(A2), UMX(A3))),
                 myumax(myumax(UMX(A4), UMX(A5)), myumax(UMX(A6), UMX(A7)))),
          myumax(myumax(myumax(UMX(A8), UMX(A9)), myumax(UMX(A10), UMX(A11))),
                 myumax(myumax(UMX(A12), UMX(A13)), myumax(UMX(A14), UMX(A15)))));
      if (!__any(mx == 0xFFFFFFFFu)) break;
    }
    float ax = -INFINITY, ay = -INFINITY, az = -INFINITY, aw = -INFINITY;
    ACCK(A0, 0)  ACCK(A1, 1)  ACCK(A2, 2)  ACCK(A3, 3)
    ACCK(A4, 4)  ACCK(A5, 5)  ACCK(A6, 6)  ACCK(A7, 7)
    ACCK(A8, 8)  ACCK(A9, 9)  ACCK(A10, 10) ACCK(A11, 11)
    ACCK(A12, 12) ACCK(A13, 13) ACCK(A14, 14) ACCK(A15, 15)
    float m = fmaxf(fmaxf(ax, ay), fmaxf(az, aw));
    // reduce over the 8 row-groups (lane bits 0..2)
    m = fmaxf(m, __shfl_xor(m, 1));
    m = fmaxf(m, __shfl_xor(m, 2));
    m = fmaxf(m, __shfl_xor(m, 4));
    if (g == 0) st_coh(scores + (size_t)t * L + col, m + e);
  }
}

// ---------------- backpointers: fully parallel recompute ----------------
#define CPB 64
__global__ __launch_bounds__(512) void bp_kernel(const float* __restrict__ trans,
                                                 const float* __restrict__ allScores,
                                                 uint16_t* __restrict__ bp) {
  extern __shared__ char smem[];
  float* Tl    = (float*)smem;                          // [L][CPB]
  float* s_lds = (float*)(smem + (size_t)L * CPB * 4);  // [L]
  float* red_v = s_lds + L;                             // [8][64]
  int*   red_i = (int*)(red_v + 8 * 64);                // [8][64]

  const int cb   = blockIdx.x & 7;
  const int tt   = blockIdx.x >> 3;
  const int tid  = threadIdx.x;
  const int wave = tid >> 6, lane = tid & 63;
  const int q = tid & 15, p = tid >> 4;
  const int col0 = cb * CPB;

  for (int idx = tid; idx < L * (CPB / 4); idx += 512) {
    int row = idx >> 4, cq = idx & 15;
    *(float4*)(Tl + row * CPB + cq * 4) =
        *(const float4*)(trans + (size_t)row * L + col0 + cq * 4);
  }
  __syncthreads();

  const int t0 = tt * 32;
  for (int dt = 0; dt < 32; ++dt) {
    int t = t0 + dt;
    if (t == 0) continue;  // uniform across block
    if (tid < L) s_lds[tid] = allScores[(size_t)(t - 1) * L + tid];
    __syncthreads();

    float bv[4]; int bi[4];
    #pragma unroll
    for (int j = 0; j < 4; ++j) { bv[j] = -INFINITY; bi[j] = 0; }
    #pragma unroll
    for (int k = 0; k < 16; ++k) {
      int i = p * 16 + k;
      float sv = s_lds[i];
      float4 tv = *(const float4*)(Tl + i * CPB + q * 4);
      float c0 = sv + tv.x, c1 = sv + tv.y, c2 = sv + tv.z, c3 = sv + tv.w;
      if (c0 > bv[0]) { bv[0] = c0; bi[0] = i; }
      if (c1 > bv[1]) { bv[1] = c1; bi[1] = i; }
      if (c2 > bv[2]) { bv[2] = c2; bi[2] = i; }
      if (c3 > bv[3]) { bv[3] = c3; bi[3] = i; }
    }
    #pragma unroll
    for (int off = 16; off <= 32; off <<= 1) {
      #pragma unroll
      for (int j = 0; j < 4; ++j) {
        float ov = __shfl_xor(bv[j], off);
        int   oi = __shfl_xor(bi[j], off);
        bool take = (ov > bv[j]) || (ov == bv[j] && oi < bi[j]);
        bv[j] = take ? ov : bv[j];
        bi[j] = take ? oi : bi[j];
      }
    }
    if (lane < 16) {
      #pragma unroll
      for (int j = 0; j < 4; ++j) {
        red_v[wave * 64 + lane * 4 + j] = bv[j];
        red_i[wave * 64 + lane * 4 + j] = bi[j];
      }
    }
    __syncthreads();
    if (wave == 0) {
      float rv = red_v[lane]; int ri = red_i[lane];
      #pragma unroll
      for (int w = 1; w < 8; ++w) {
        float ov = red_v[w * 64 + lane]; int oi = red_i[w * 64 + lane];
        bool take = (ov > rv) || (ov == rv && oi < ri);
        rv = take ? ov : rv; ri = take ? oi : ri;
      }
      bp[(size_t)t * L + col0 + lane] = (uint16_t)ri;
    }
    __syncthreads();
  }
}

// ---------------- backtrack phase A: per-chunk label maps ----------------
__global__ __launch_bounds__(512) void exitmap_kernel(const uint16_t* __restrict__ bp,
                                                      uint16_t* __restrict__ cexit) {
  extern __shared__ char smem[];
  uint16_t* bpl = (uint16_t*)smem;  // [nrows][L]
  const int c = blockIdx.x, tid = threadIdx.x;
  const int lo = c * CHUNK;
  const int hi = min(lo + CHUNK, TSTEPS - 1);
  const int nrows = hi - lo;
  const uint32_t* src = (const uint32_t*)(bp + (size_t)(lo + 1) * L);
  uint32_t* dst = (uint32_t*)bpl;
  for (int idx = tid; idx < nrows * (L / 2); idx += 512) dst[idx] = src[idx];
  __syncthreads();
  int e = tid;
  for (int r = nrows - 1; r >= 0; --r) e = bpl[r * L + e];
  cexit[(size_t)c * L + tid] = (uint16_t)e;
}

// ---------------- backtrack phase B: final argmax + chunk composition ----------------
__global__ __launch_bounds__(64) void compose_kernel(const float* __restrict__ allScores,
                                                     const uint16_t* __restrict__ cexit,
                                                     int* __restrict__ entryTag,
                                                     float* __restrict__ out) {
  const int lane = threadIdx.x;
  float bv = -INFINITY; int bi = 0;
  #pragma unroll
  for (int r = 0; r < 8; ++r) {
    int i = r * 64 + lane;
    float v = allScores[(size_t)(TSTEPS - 1) * L + i];
    if (v > bv) { bv = v; bi = i; }
  }
  #pragma unroll
  for (int off = 1; off < 64; off <<= 1) {
    float ov = __shfl_xor(bv, off);
    int   oi = __shfl_xor(bi, off);
    bool take = (ov > bv) || (ov == bv && oi < bi);
    bv = take ? ov : bv; bi = take ? oi : bi;
  }
  if (lane == 0) {
    out[0] = bv;
    out[1 + (TSTEPS - 1)] = (float)bi;
    int e = bi;
    entryTag[NCHUNK - 1] = e;
    for (int c = NCHUNK - 1; c >= 1; --c) {
      e = cexit[(size_t)c * L + e];
      entryTag[c - 1] = e;
    }
  }
}

// ---------------- backtrack phase C: per-chunk path extraction ----------------
__global__ __launch_bounds__(512) void extract_kernel(const uint16_t* __restrict__ bp,
                                                      const int* __restrict__ entryTag,
                                                      float* __restrict__ out) {
  extern __shared__ char smem[];
  uint16_t* bpl = (uint16_t*)smem;
  const int c = blockIdx.x, tid = threadIdx.x;
  const int lo = c * CHUNK;
  const int hi = min(lo + CHUNK, TSTEPS - 1);
  const int nrows = hi - lo;
  const uint32_t* src = (const uint32_t*)(bp + (size_t)(lo + 1) * L);
  uint32_t* dst = (uint32_t*)bpl;
  for (int idx = tid; idx < nrows * (L / 2); idx += 512) dst[idx] = src[idx];
  __syncthreads();
  if (tid == 0) {
    int e = entryTag[c];
    for (int t = hi - 1; t >= lo; --t) {
      e = bpl[(t - lo) * L + e];
      out[1 + t] = (float)e;
    }
  }
}

extern "C" void kernel_launch(void* const* d_in, const int* in_sizes, int n_in,
                              void* d_out, int out_size, void* d_ws, size_t ws_size,
                              hipStream_t stream) {
  const float* feats = (const float*)d_in[0];
  const float* trans = (const float*)d_in[1];
  float* out = (float*)d_out;
  char* ws = (char*)d_ws;
  float*    allScores = (float*)(ws + OFF_SCORES);
  uint16_t* bp        = (uint16_t*)(ws + OFF_BP);
  uint16_t* cexit     = (uint16_t*)(ws + OFF_EXIT);
  int*      entryTag  = (int*)(ws + OFF_ENTRY);

  const int BP_LDS  = L * CPB * 4 + L * 4 + 8 * 64 * 4 + 8 * 64 * 4;  // 137216
  const int CH_LDS  = CHUNK * L * 2;                                  // 131072

  hipFuncSetAttribute((const void*)bp_kernel,      hipFuncAttributeMaxDynamicSharedMemorySize, BP_LDS);
  hipFuncSetAttribute((const void*)exitmap_kernel, hipFuncAttributeMaxDynamicSharedMemorySize, CH_LDS);
  hipFuncSetAttribute((const void*)extract_kernel, hipFuncAttributeMaxDynamicSharedMemorySize, CH_LDS);

  // NaN-sentinel the score exchange buffer (replay-safe; part of the graph)
  hipMemsetAsync(allScores, 0xFF, (size_t)TSTEPS * L * sizeof(float), stream);

  fwd_kernel<<<64, 64, 0, stream>>>(feats, trans, allScores);
  bp_kernel<<<(TSTEPS / 32) * 8, 512, BP_LDS, stream>>>(trans, allScores, bp);
  exitmap_kernel<<<NCHUNK, 512, CH_LDS, stream>>>(bp, cexit);
  compose_kernel<<<1, 64, 0, stream>>>(allScores, cexit, entryTag, out);
  extract_kernel<<<NCHUNK, 512, CH_LDS, stream>>>(bp, entryTag, out);
}